// Round 4
// baseline (207.170 us; speedup 1.0000x reference)
//
#include <hip/hip_runtime.h>
#include <cstdint>

#define B_   32
#define CIN  256
#define COUT 256
#define H_   56
#define W_   56
#define HP   58          // padded spatial dim (pad=1 each side)
#define HW   (H_ * W_)   // 3136
#define HP8  (HP * 8)

typedef int v4i  __attribute__((ext_vector_type(4)));
typedef int v16i __attribute__((ext_vector_type(16)));

// ==================================================================
// MFMA path: a,w in {+1,-1} as i8; zero-pad = i8 0 (exact, no corr).
// ==================================================================

// ---- pack_a8: NCHW fp32 -> padded NHWC i8. A8[b][hh][ww][ci] ----
__global__ __launch_bounds__(256) void pack_a8_kernel(
    const float* __restrict__ x, const float* __restrict__ alpha,
    char* __restrict__ A8) {
  const int w = threadIdx.x & 63;
  const int q = threadIdx.x >> 6;
  const int hh = blockIdx.x * 4 + q;
  const int b = blockIdx.y;
  if (hh >= HP) return;
  char* rowbase = A8 + (size_t)(b * HP + hh) * (HP * 256);
  const uint4 z = make_uint4(0u, 0u, 0u, 0u);
  if (hh == 0 || hh == HP - 1) {           // border row: all zeros
    for (int i = w + q * 0; i < HP * 16; i += 64) *(uint4*)(rowbase + i * 16) = z;
    return;
  }
  const int h = hh - 1;
  if (w < W_) {
    char* dst = rowbase + (w + 1) * 256;
    const float* xp = x + (size_t)b * CIN * HW + h * W_ + w;
    for (int cw = 0; cw < 16; ++cw) {      // 16B of channels per iter
      uint32_t wd[4];
      #pragma unroll
      for (int u = 0; u < 4; ++u) {
        uint32_t word = 0;
        #pragma unroll
        for (int bb = 0; bb < 4; ++bb) {
          int c = cw * 16 + u * 4 + bb;
          float v = xp[(size_t)c * HW];
          word |= ((v > alpha[c]) ? 0x01u : 0xFFu) << (bb * 8);
        }
        wd[u] = word;
      }
      *(uint4*)(dst + cw * 16) = *(uint4*)wd;
    }
  } else if (w == 56 || w == 57) {         // border pixels ww=0 / ww=57
    char* dst = rowbase + ((w == 56) ? 0 : (HP - 1)) * 256;
    #pragma unroll
    for (int i = 0; i < 16; ++i) *(uint4*)(dst + i * 16) = z;
  }
}

// ---- pack_w8: pack W into exact B-fragment form ----
// Wf[((tap*8 + kc)*8 + ng)*64 + lane] = 16 i8: co = ng*32 + (lane&31),
// ci = kc*32 + (lane>>5)*16 + j  (j = little-endian byte index)
__global__ __launch_bounds__(256) void pack_w8_kernel(
    const float* __restrict__ wt, v4i* __restrict__ Wf) {
  int id = blockIdx.x * 256 + threadIdx.x;   // 36864 total
  int lane = id & 63;
  int ng = (id >> 6) & 7;
  int kc = (id >> 9) & 7;
  int tap = id >> 12;
  if (tap >= 9) return;
  int kh = tap / 3, kw = tap - kh * 3;
  int co = ng * 32 + (lane & 31);
  int cib = kc * 32 + (lane >> 5) * 16;
  uint32_t wd[4];
  #pragma unroll
  for (int u = 0; u < 4; ++u) {
    uint32_t word = 0;
    #pragma unroll
    for (int bb = 0; bb < 4; ++bb) {
      int ci = cib + u * 4 + bb;
      float v = wt[((size_t)(co * CIN + ci) * 3 + kh) * 3 + kw];
      word |= ((v > 0.0f) ? 0x01u : 0xFFu) << (bb * 8);
    }
    wd[u] = word;
  }
  Wf[id] = *(v4i*)wd;
}

// ---- conv_mfma: block = M128 (2 oh x 64 ow) x N256, 4 waves ----
// wave = M128 x N64 (ng = wid*2, wid*2+1); acc = 4mg x 2ng v16i.
// A staged in LDS [4 rows][58][256] i8, XOR-swizzled (granule ^ ww&15).
#define NWWC 58
__global__ __launch_bounds__(256, 2) void conv_mfma_kernel(
    const char* __restrict__ A8, const v4i* __restrict__ Wf,
    float* __restrict__ out) {
  __shared__ alignas(16) char lds[4 * NWWC * 256];   // 59392 B
  const int tid = threadIdx.x;
  const int lane = tid & 63;
  const int wid = tid >> 6;
  const int ohp = blockIdx.x % 28;
  const int b   = blockIdx.x / 28;
  const int oh0 = ohp * 2;

  // fill LDS: contiguous copy of rows oh0..oh0+3, swizzled dest
  {
    const char* src0 = A8 + (size_t)(b * HP + oh0) * (HP * 256);
    for (int i = tid; i < 4 * NWWC * 16; i += 256) {
      int rowidx = i >> 4;              // rr*58 + ww
      int gr = i & 15;
      int ww = rowidx % NWWC;
      uint4 v = *(const uint4*)(src0 + (size_t)rowidx * 256 + gr * 16);
      int phys = (rowidx * 256 + gr * 16) ^ ((ww & 15) << 4);
      *(uint4*)(lds + phys) = v;
    }
  }
  __syncthreads();

  const int l31 = lane & 31;
  const int lh16 = (lane >> 5) * 16;

  v16i zero_v;
  #pragma unroll
  for (int e = 0; e < 16; ++e) zero_v[e] = 0;
  v16i acc[4][2];
  #pragma unroll
  for (int m = 0; m < 4; ++m) {
    #pragma unroll
    for (int n = 0; n < 2; ++n) acc[m][n] = zero_v;
  }

  const v4i* wfl = Wf + (wid * 2) * 64 + lane;

  #pragma unroll
  for (int kh = 0; kh < 3; ++kh) {
    #pragma unroll
    for (int kw = 0; kw < 3; ++kw) {
      const int tap = kh * 3 + kw;
      int rbase[4], sw[4];
      #pragma unroll
      for (int mg = 0; mg < 4; ++mg) {
        int ww = (mg & 1) * 32 + l31 + kw;
        int wwc = ww > 57 ? 57 : ww;     // ow>=56 is padding garbage
        int rr = (mg >> 1) + kh;
        rbase[mg] = (rr * NWWC + wwc) * 256;
        sw[mg] = (wwc & 15) << 4;
      }
      #pragma unroll
      for (int kc = 0; kc < 8; ++kc) {
        v4i bf0 = wfl[(tap * 8 + kc) * 512];
        v4i bf1 = wfl[(tap * 8 + kc) * 512 + 64];
        int g = kc * 32 + lh16;
        #pragma unroll
        for (int mg = 0; mg < 4; ++mg) {
          v4i af = *(const v4i*)(lds + (rbase[mg] + (g ^ sw[mg])));
          acc[mg][0] = __builtin_amdgcn_mfma_i32_32x32x32_i8(af, bf0, acc[mg][0], 0, 0, 0);
          acc[mg][1] = __builtin_amdgcn_mfma_i32_32x32x32_i8(af, bf1, acc[mg][1], 0, 0, 0);
        }
      }
    }
  }

  // epilogue: C/D 32x32 layout: n = lane&31, m = (reg&3)+8*(reg>>2)+4*(lane>>5)
  #pragma unroll
  for (int mg = 0; mg < 4; ++mg) {
    #pragma unroll
    for (int nl = 0; nl < 2; ++nl) {
      int co = (wid * 2 + nl) * 32 + l31;
      float* ob = out + (size_t)(b * COUT + co) * HW;
      #pragma unroll
      for (int qd = 0; qd < 4; ++qd) {
        int m0 = mg * 32 + qd * 8 + (lh16 >> 2);
        int ow0 = m0 & 63;
        if (ow0 <= 52) {                 // skip ow 56..63 padding columns
          int p = m0 >> 6;
          float4 f;
          f.x = (float)acc[mg][nl][qd * 4 + 0];
          f.y = (float)acc[mg][nl][qd * 4 + 1];
          f.z = (float)acc[mg][nl][qd * 4 + 2];
          f.w = (float)acc[mg][nl][qd * 4 + 3];
          *(float4*)(ob + (size_t)(oh0 + p) * W_ + ow0) = f;
        }
      }
    }
  }
}

// ==================================================================
// Fallback popcount path (round-3, passed @156us) if ws too small
// ==================================================================
__global__ __launch_bounds__(256) void pack_a_kernel(
    const float* __restrict__ x, const float* __restrict__ alpha,
    uint32_t* __restrict__ Ap) {
  int ww = threadIdx.x & 63;
  int q  = threadIdx.x >> 6;
  int hh = blockIdx.x * 4 + q;
  int b  = blockIdx.y;
  if (hh >= HP || ww >= HP) return;
  uint32_t* dst = Ap + (((b * HP + hh) * HP + ww) * 8);
  if (hh == 0 || hh == HP - 1 || ww == 0 || ww == HP - 1) {
    uint4 z = make_uint4(0u, 0u, 0u, 0u);
    *(uint4*)dst = z;
    *(uint4*)(dst + 4) = z;
    return;
  }
  int h = hh - 1, w = ww - 1;
  const float* xp = x + (size_t)b * CIN * HW + h * W_ + w;
  uint32_t wv[8];
  #pragma unroll
  for (int k = 0; k < 8; ++k) {
    uint32_t cur = 0u;
    #pragma unroll
    for (int i = 0; i < 32; ++i) {
      int c = k * 32 + i;
      float d = xp[c * HW] - alpha[c];
      cur |= (d > 0.0f) ? (1u << i) : 0u;
    }
    wv[k] = cur;
  }
  *(uint4*)dst       = *(uint4*)&wv[0];
  *(uint4*)(dst + 4) = *(uint4*)&wv[4];
}

__global__ __launch_bounds__(256) void pack_w_kernel(
    const float* __restrict__ wt, uint32_t* __restrict__ Wp,
    uint32_t* __restrict__ pw) {
  int t = blockIdx.x * 256 + threadIdx.x;
  if (t >= COUT * 9) return;
  int co = t / 9;
  int tap = t - co * 9;
  const float* w0 = wt + (size_t)co * CIN * 9 + tap;
  int pc = 0;
  #pragma unroll
  for (int k = 0; k < 8; ++k) {
    uint32_t cur = 0u;
    #pragma unroll
    for (int i = 0; i < 32; ++i) {
      float v = w0[(k * 32 + i) * 9];
      cur |= (v > 0.0f) ? (1u << i) : 0u;
    }
    Wp[((tap * COUT + co) * 8) + k] = cur;
    pc += __popc(cur);
  }
  pw[tap * COUT + co] = (uint32_t)pc;
}

#define NCO 8
#define OHT 2
__global__ __launch_bounds__(256, 4) void conv_kernel(
    const uint32_t* __restrict__ Ap, const uint32_t* __restrict__ Wp,
    const uint32_t* __restrict__ pw, float* __restrict__ out) {
  const int ow = threadIdx.x & 63;
  const int q  = threadIdx.x >> 6;
  if (ow >= W_) return;
  const int r0  = blockIdx.y * (4 * OHT) + q * OHT;
  const int co0 = blockIdx.x * NCO;
  const int b   = blockIdx.z;
  const uint32_t* ap = Ap + (((b * HP + r0) * HP + ow) * 8);
  uint32_t rA[24], rB[24], rC[24];
#define LOAD_ROW(dst, off) do {                                   \
    *(uint4*)&(dst)[0]  = *(const uint4*)(ap + (off));            \
    *(uint4*)&(dst)[4]  = *(const uint4*)(ap + (off) + 4);        \
    *(uint4*)&(dst)[8]  = *(const uint4*)(ap + (off) + 8);        \
    *(uint4*)&(dst)[12] = *(const uint4*)(ap + (off) + 12);       \
    *(uint4*)&(dst)[16] = *(const uint4*)(ap + (off) + 16);       \
    *(uint4*)&(dst)[20] = *(const uint4*)(ap + (off) + 20);       \
  } while (0)
  LOAD_ROW(rA, 0);
  LOAD_ROW(rB, HP8);
  LOAD_ROW(rC, 2 * HP8);
  int acc0[NCO], acc1[NCO];
  #pragma unroll
  for (int c = 0; c < NCO; ++c) { acc0[c] = 0; acc1[c] = 0; }
#define PROC(x0, x1, tb) do {                                     \
    _Pragma("unroll")                                             \
    for (int kw = 0; kw < 3; ++kw) {                              \
      const uint32_t* wb = Wp + (((tb) + kw) * COUT + co0) * 8;   \
      _Pragma("unroll")                                           \
      for (int c = 0; c < NCO; ++c) {                             \
        _Pragma("unroll")                                         \
        for (int j = 0; j < 8; ++j) {                             \
          uint32_t w  = wb[c * 8 + j];                            \
          uint32_t t0 = (x0)[kw * 8 + j] ^ w;                     \
          uint32_t t1 = (x1)[kw * 8 + j] ^ w;                     \
          asm("v_bcnt_u32_b32 %0, %1, %0" : "+v"(acc0[c]) : "v"(t0)); \
          asm("v_bcnt_u32_b32 %0, %1, %0" : "+v"(acc1[c]) : "v"(t1)); \
        }                                                         \
      }                                                           \
    }                                                             \
  } while (0)
  PROC(rA, rB, 0);
  LOAD_ROW(rA, 3 * HP8);
  PROC(rB, rC, 3);
  PROC(rC, rA, 6);
#undef PROC
#undef LOAD_ROW
  int corr0[NCO], corr1[NCO];
  #pragma unroll
  for (int c = 0; c < NCO; ++c) { corr0[c] = 0; corr1[c] = 0; }
  const bool left = (ow == 0), right = (ow == W_ - 1);
  {
    const bool top = (r0 == 0), bot = (r0 == H_ - 1);
    if (top || bot || left || right) {
      #pragma unroll
      for (int kh = 0; kh < 3; ++kh)
        #pragma unroll
        for (int kw = 0; kw < 3; ++kw) {
          bool inv = (top && kh == 0) || (bot && kh == 2) ||
                     (left && kw == 0) || (right && kw == 2);
          if (inv)
            #pragma unroll
            for (int c = 0; c < NCO; ++c)
              corr0[c] += 256 - 2 * (int)pw[(kh * 3 + kw) * COUT + co0 + c];
        }
    }
  }
  {
    const int r = r0 + 1;
    const bool top = (r == 0), bot = (r == H_ - 1);
    if (top || bot || left || right) {
      #pragma unroll
      for (int kh = 0; kh < 3; ++kh)
        #pragma unroll
        for (int kw = 0; kw < 3; ++kw) {
          bool inv = (top && kh == 0) || (bot && kh == 2) ||
                     (left && kw == 0) || (right && kw == 2);
          if (inv)
            #pragma unroll
            for (int c = 0; c < NCO; ++c)
              corr1[c] += 256 - 2 * (int)pw[(kh * 3 + kw) * COUT + co0 + c];
        }
    }
  }
  const int ob = ((b * COUT + co0) * H_ + r0) * W_ + ow;
  #pragma unroll
  for (int c = 0; c < NCO; ++c) {
    out[ob + c * HW]      = (float)(9 * 256 - 2 * acc0[c] - corr0[c]);
    out[ob + c * HW + W_] = (float)(9 * 256 - 2 * acc1[c] - corr1[c]);
  }
}

// ==================================================================
extern "C" void kernel_launch(void* const* d_in, const int* in_sizes, int n_in,
                              void* d_out, int out_size, void* d_ws, size_t ws_size,
                              hipStream_t stream) {
  const float* x     = (const float*)d_in[0];
  const float* alpha = (const float*)d_in[1];
  const float* wt    = (const float*)d_in[2];
  float* out = (float*)d_out;

  const size_t needA = (size_t)B_ * HP * HP * 256;   // 27,557,888 B
  const size_t needW = (size_t)9 * 8 * 8 * 64 * 16;  //    589,824 B

  if (ws_size >= needA + needW) {
    char* A8 = (char*)d_ws;
    v4i* Wf  = (v4i*)(A8 + needA);
    pack_a8_kernel<<<dim3(15, 32), 256, 0, stream>>>(x, alpha, A8);
    pack_w8_kernel<<<144, 256, 0, stream>>>(wt, Wf);
    conv_mfma_kernel<<<dim3(32 * 28), 256, 0, stream>>>(A8, Wf, out);
  } else {
    uint32_t* Ap = (uint32_t*)d_ws;
    uint32_t* Wp = Ap + (size_t)B_ * HP * HP * 8;
    uint32_t* pw = Wp + (size_t)9 * COUT * 8;
    dim3 gA((HP + 3) / 4, B_);
    pack_a_kernel<<<gA, 256, 0, stream>>>(x, alpha, Ap);
    pack_w_kernel<<<9, 256, 0, stream>>>(wt, Wp, pw);
    dim3 gC(COUT / NCO, H_ / (4 * OHT), B_);
    conv_kernel<<<gC, 256, 0, stream>>>(Ap, Wp, pw, out);
  }
}

// Round 5
// 164.817 us; speedup vs baseline: 1.2570x; 1.2570x over previous
//
#include <hip/hip_runtime.h>
#include <cstdint>

#define B_   32
#define CIN  256
#define COUT 256
#define H_   56
#define W_   56
#define HP   58          // padded spatial dim (pad=1 each side)
#define HW   (H_ * W_)   // 3136
#define HP8  (HP * 8)

typedef int v4i  __attribute__((ext_vector_type(4)));
typedef int v16i __attribute__((ext_vector_type(16)));

// ==================================================================
// MFMA path: a,w in {+1,-1} as i8; zero-pad = i8 0 (exact, no corr).
// ==================================================================

// ---- pack_a8: NCHW fp32 -> padded NHWC i8. A8[b][hh][ww][ci] ----
__global__ __launch_bounds__(256) void pack_a8_kernel(
    const float* __restrict__ x, const float* __restrict__ alpha,
    char* __restrict__ A8) {
  const int w = threadIdx.x & 63;
  const int q = threadIdx.x >> 6;
  const int hh = blockIdx.x * 4 + q;
  const int b = blockIdx.y;
  if (hh >= HP) return;
  char* rowbase = A8 + (size_t)(b * HP + hh) * (HP * 256);
  const uint4 z = make_uint4(0u, 0u, 0u, 0u);
  if (hh == 0 || hh == HP - 1) {           // border row: all zeros
    for (int i = w; i < HP * 16; i += 64) *(uint4*)(rowbase + i * 16) = z;
    return;
  }
  const int h = hh - 1;
  if (w < W_) {
    char* dst = rowbase + (w + 1) * 256;
    const float* xp = x + (size_t)b * CIN * HW + h * W_ + w;
    for (int cw = 0; cw < 16; ++cw) {      // 16B of channels per iter
      uint32_t wd[4];
      #pragma unroll
      for (int u = 0; u < 4; ++u) {
        uint32_t word = 0;
        #pragma unroll
        for (int bb = 0; bb < 4; ++bb) {
          int c = cw * 16 + u * 4 + bb;
          float v = xp[(size_t)c * HW];
          word |= ((v > alpha[c]) ? 0x01u : 0xFFu) << (bb * 8);
        }
        wd[u] = word;
      }
      *(uint4*)(dst + cw * 16) = *(uint4*)wd;
    }
  } else if (w == 56 || w == 57) {         // border pixels ww=0 / ww=57
    char* dst = rowbase + ((w == 56) ? 0 : (HP - 1)) * 256;
    #pragma unroll
    for (int i = 0; i < 16; ++i) *(uint4*)(dst + i * 16) = z;
  }
}

// ---- pack_w8: pack W into exact B-fragment form ----
// Wf[((tap*8 + kc)*8 + ng)*64 + lane] = 16 i8: co = ng*32 + (lane&31),
// ci = kc*32 + (lane>>5)*16 + j  (j = little-endian byte index)
__global__ __launch_bounds__(256) void pack_w8_kernel(
    const float* __restrict__ wt, v4i* __restrict__ Wf) {
  int id = blockIdx.x * 256 + threadIdx.x;   // 36864 total
  int lane = id & 63;
  int ng = (id >> 6) & 7;
  int kc = (id >> 9) & 7;
  int tap = id >> 12;
  if (tap >= 9) return;
  int kh = tap / 3, kw = tap - kh * 3;
  int co = ng * 32 + (lane & 31);
  int cib = kc * 32 + (lane >> 5) * 16;
  uint32_t wd[4];
  #pragma unroll
  for (int u = 0; u < 4; ++u) {
    uint32_t word = 0;
    #pragma unroll
    for (int bb = 0; bb < 4; ++bb) {
      int ci = cib + u * 4 + bb;
      float v = wt[((size_t)(co * CIN + ci) * 3 + kh) * 3 + kw];
      word |= ((v > 0.0f) ? 0x01u : 0xFFu) << (bb * 8);
    }
    wd[u] = word;
  }
  Wf[id] = *(v4i*)wd;
}

// ---- conv_mfma v2 ----
// Block 256 thr = 4 waves. Block tile: M64 (2 oh x 28 ow chunk) x N256.
// Wave wn: M64 x N64 (ng pair 2wn, 2wn+1); acc = 2mg x 2ng v16i = 64 VGPR.
// LDS: TRANSPOSED A slab lds_t[gr 16][rr 4][ww 35pad] x 16B = 35,840 B.
//  -> af reads: consecutive lanes hit consecutive 16B slots (conflict-free),
//     addr = thread-base + compile-time immediate (no inner-loop VALU).
// Epilogue: C tiles transposed through (dead) LDS slab -> coalesced stores.
#define WWIN 34
#define WPAD 35
#define OWC  28
__global__ __launch_bounds__(256, 4) void conv_mfma_kernel(
    const char* __restrict__ A8, const v4i* __restrict__ Wf,
    float* __restrict__ out) {
  __shared__ alignas(16) char lds[16 * 4 * WPAD * 16];   // 35,840 B
  const int tid = threadIdx.x;
  const int lane = tid & 63;
  const int l31 = lane & 31;
  const int hi = lane >> 5;
  const int wn = tid >> 6;

  const int bx = blockIdx.x;
  const int owc = bx & 1;
  const int rest = bx >> 1;
  const int ohp = rest % 28;
  const int b = rest / 28;
  const int oh0 = ohp * 2;
  const int owbase = owc * OWC;

  // ---- fill LDS (transposed): 4 rows x 34 ww x 16 granules ----
  {
    const char* src0 = A8 + (size_t)(b * HP + oh0) * (HP * 256) + owbase * 256;
    for (int i = tid; i < 4 * WWIN * 16; i += 256) {
      int gr = i & 15;
      int pix = i >> 4;            // rr*34 + ww
      int rr = pix / WWIN;
      int ww = pix - rr * WWIN;
      uint4 v = make_uint4(0u, 0u, 0u, 0u);
      if (owbase + ww <= HP - 1)
        v = *(const uint4*)(src0 + (size_t)(rr * HP + ww) * 256 + gr * 16);
      *(uint4*)(lds + ((gr * 4 + rr) * WPAD + ww) * 16) = v;
    }
  }
  __syncthreads();

  v16i zero_v;
  #pragma unroll
  for (int e = 0; e < 16; ++e) zero_v[e] = 0;
  v16i acc[2][2];
  acc[0][0] = zero_v; acc[0][1] = zero_v;
  acc[1][0] = zero_v; acc[1][1] = zero_v;

  // thread-constant part of the LDS A address
  const char* abase = lds + hi * 2240 + l31 * 16;
  const v4i* wfl = Wf + (wn * 2) * 64 + lane;   // ng0 = 2*wn

  #pragma unroll
  for (int kh = 0; kh < 3; ++kh) {
    #pragma unroll
    for (int kw = 0; kw < 3; ++kw) {
      const int tap = kh * 3 + kw;
      #pragma unroll
      for (int kc = 0; kc < 8; ++kc) {
        v4i bf0 = wfl[(tap * 8 + kc) * 512];
        v4i bf1 = wfl[(tap * 8 + kc) * 512 + 64];
        // af byte offset = kc*4480 + (kh+mg)*560 + kw*16 (compile-time imm)
        v4i af0 = *(const v4i*)(abase + kc * 4480 + (kh + 0) * 560 + kw * 16);
        v4i af1 = *(const v4i*)(abase + kc * 4480 + (kh + 1) * 560 + kw * 16);
        acc[0][0] = __builtin_amdgcn_mfma_i32_32x32x32_i8(af0, bf0, acc[0][0], 0, 0, 0);
        acc[0][1] = __builtin_amdgcn_mfma_i32_32x32x32_i8(af0, bf1, acc[0][1], 0, 0, 0);
        acc[1][0] = __builtin_amdgcn_mfma_i32_32x32x32_i8(af1, bf0, acc[1][0], 0, 0, 0);
        acc[1][1] = __builtin_amdgcn_mfma_i32_32x32x32_i8(af1, bf1, acc[1][1], 0, 0, 0);
      }
    }
  }

  // ---- epilogue: transpose each 32x32 tile through LDS, store coalesced ----
  __syncthreads();                        // A slab now dead for ALL waves
  float* scr = (float*)(lds + wn * (32 * 36 * 4));   // 4,608 B per wave

  #pragma unroll
  for (int mg = 0; mg < 2; ++mg) {
    #pragma unroll
    for (int nl = 0; nl < 2; ++nl) {
      // write: lane holds col(co)=l31, rows m = 8q+4hi+0..3
      #pragma unroll
      for (int q = 0; q < 4; ++q) {
        float4 f;
        f.x = (float)acc[mg][nl][q * 4 + 0];
        f.y = (float)acc[mg][nl][q * 4 + 1];
        f.z = (float)acc[mg][nl][q * 4 + 2];
        f.w = (float)acc[mg][nl][q * 4 + 3];
        *(float4*)(scr + l31 * 36 + 8 * q + 4 * hi) = f;
      }
      __builtin_amdgcn_s_waitcnt(0);      // drain lgkm before re-read (same wave)
      // read transposed: co_l = p*8 + (lane>>3), ow quad = (lane&7)*4
      const int co = (wn * 2 + nl) * 32;
      const int oh = oh0 + mg;
      #pragma unroll
      for (int p = 0; p < 4; ++p) {
        int co_l = p * 8 + (lane >> 3);
        int owq = (lane & 7) * 4;
        float4 v = *(const float4*)(scr + co_l * 36 + owq);
        if (owq < OWC) {
          float* op = out + ((size_t)(b * COUT + co + co_l) * H_ + oh) * W_ + owbase + owq;
          *(float4*)op = v;
        }
      }
      __builtin_amdgcn_s_waitcnt(0);      // finish reads before next tile's writes
    }
  }
}

// ==================================================================
// Fallback popcount path (round-3, 156us) if ws too small
// ==================================================================
__global__ __launch_bounds__(256) void pack_a_kernel(
    const float* __restrict__ x, const float* __restrict__ alpha,
    uint32_t* __restrict__ Ap) {
  int ww = threadIdx.x & 63;
  int q  = threadIdx.x >> 6;
  int hh = blockIdx.x * 4 + q;
  int b  = blockIdx.y;
  if (hh >= HP || ww >= HP) return;
  uint32_t* dst = Ap + (((b * HP + hh) * HP + ww) * 8);
  if (hh == 0 || hh == HP - 1 || ww == 0 || ww == HP - 1) {
    uint4 z = make_uint4(0u, 0u, 0u, 0u);
    *(uint4*)dst = z;
    *(uint4*)(dst + 4) = z;
    return;
  }
  int h = hh - 1, w = ww - 1;
  const float* xp = x + (size_t)b * CIN * HW + h * W_ + w;
  uint32_t wv[8];
  #pragma unroll
  for (int k = 0; k < 8; ++k) {
    uint32_t cur = 0u;
    #pragma unroll
    for (int i = 0; i < 32; ++i) {
      int c = k * 32 + i;
      float d = xp[c * HW] - alpha[c];
      cur |= (d > 0.0f) ? (1u << i) : 0u;
    }
    wv[k] = cur;
  }
  *(uint4*)dst       = *(uint4*)&wv[0];
  *(uint4*)(dst + 4) = *(uint4*)&wv[4];
}

__global__ __launch_bounds__(256) void pack_w_kernel(
    const float* __restrict__ wt, uint32_t* __restrict__ Wp,
    uint32_t* __restrict__ pw) {
  int t = blockIdx.x * 256 + threadIdx.x;
  if (t >= COUT * 9) return;
  int co = t / 9;
  int tap = t - co * 9;
  const float* w0 = wt + (size_t)co * CIN * 9 + tap;
  int pc = 0;
  #pragma unroll
  for (int k = 0; k < 8; ++k) {
    uint32_t cur = 0u;
    #pragma unroll
    for (int i = 0; i < 32; ++i) {
      float v = w0[(k * 32 + i) * 9];
      cur |= (v > 0.0f) ? (1u << i) : 0u;
    }
    Wp[((tap * COUT + co) * 8) + k] = cur;
    pc += __popc(cur);
  }
  pw[tap * COUT + co] = (uint32_t)pc;
}

#define NCO 8
#define OHT 2
__global__ __launch_bounds__(256, 4) void conv_kernel(
    const uint32_t* __restrict__ Ap, const uint32_t* __restrict__ Wp,
    const uint32_t* __restrict__ pw, float* __restrict__ out) {
  const int ow = threadIdx.x & 63;
  const int q  = threadIdx.x >> 6;
  if (ow >= W_) return;
  const int r0  = blockIdx.y * (4 * OHT) + q * OHT;
  const int co0 = blockIdx.x * NCO;
  const int b   = blockIdx.z;
  const uint32_t* ap = Ap + (((b * HP + r0) * HP + ow) * 8);
  uint32_t rA[24], rB[24], rC[24];
#define LOAD_ROW(dst, off) do {                                   \
    *(uint4*)&(dst)[0]  = *(const uint4*)(ap + (off));            \
    *(uint4*)&(dst)[4]  = *(const uint4*)(ap + (off) + 4);        \
    *(uint4*)&(dst)[8]  = *(const uint4*)(ap + (off) + 8);        \
    *(uint4*)&(dst)[12] = *(const uint4*)(ap + (off) + 12);       \
    *(uint4*)&(dst)[16] = *(const uint4*)(ap + (off) + 16);       \
    *(uint4*)&(dst)[20] = *(const uint4*)(ap + (off) + 20);       \
  } while (0)
  LOAD_ROW(rA, 0);
  LOAD_ROW(rB, HP8);
  LOAD_ROW(rC, 2 * HP8);
  int acc0[NCO], acc1[NCO];
  #pragma unroll
  for (int c = 0; c < NCO; ++c) { acc0[c] = 0; acc1[c] = 0; }
#define PROC(x0, x1, tb) do {                                     \
    _Pragma("unroll")                                             \
    for (int kw = 0; kw < 3; ++kw) {                              \
      const uint32_t* wb = Wp + (((tb) + kw) * COUT + co0) * 8;   \
      _Pragma("unroll")                                           \
      for (int c = 0; c < NCO; ++c) {                             \
        _Pragma("unroll")                                         \
        for (int j = 0; j < 8; ++j) {                             \
          uint32_t w  = wb[c * 8 + j];                            \
          uint32_t t0 = (x0)[kw * 8 + j] ^ w;                     \
          uint32_t t1 = (x1)[kw * 8 + j] ^ w;                     \
          asm("v_bcnt_u32_b32 %0, %1, %0" : "+v"(acc0[c]) : "v"(t0)); \
          asm("v_bcnt_u32_b32 %0, %1, %0" : "+v"(acc1[c]) : "v"(t1)); \
        }                                                         \
      }                                                           \
    }                                                             \
  } while (0)
  PROC(rA, rB, 0);
  LOAD_ROW(rA, 3 * HP8);
  PROC(rB, rC, 3);
  PROC(rC, rA, 6);
#undef PROC
#undef LOAD_ROW
  int corr0[NCO], corr1[NCO];
  #pragma unroll
  for (int c = 0; c < NCO; ++c) { corr0[c] = 0; corr1[c] = 0; }
  const bool left = (ow == 0), right = (ow == W_ - 1);
  {
    const bool top = (r0 == 0), bot = (r0 == H_ - 1);
    if (top || bot || left || right) {
      #pragma unroll
      for (int kh = 0; kh < 3; ++kh)
        #pragma unroll
        for (int kw = 0; kw < 3; ++kw) {
          bool inv = (top && kh == 0) || (bot && kh == 2) ||
                     (left && kw == 0) || (right && kw == 2);
          if (inv)
            #pragma unroll
            for (int c = 0; c < NCO; ++c)
              corr0[c] += 256 - 2 * (int)pw[(kh * 3 + kw) * COUT + co0 + c];
        }
    }
  }
  {
    const int r = r0 + 1;
    const bool top = (r == 0), bot = (r == H_ - 1);
    if (top || bot || left || right) {
      #pragma unroll
      for (int kh = 0; kh < 3; ++kh)
        #pragma unroll
        for (int kw = 0; kw < 3; ++kw) {
          bool inv = (top && kh == 0) || (bot && kh == 2) ||
                     (left && kw == 0) || (right && kw == 2);
          if (inv)
            #pragma unroll
            for (int c = 0; c < NCO; ++c)
              corr1[c] += 256 - 2 * (int)pw[(kh * 3 + kw) * COUT + co0 + c];
        }
    }
  }
  const int ob = ((b * COUT + co0) * H_ + r0) * W_ + ow;
  #pragma unroll
  for (int c = 0; c < NCO; ++c) {
    out[ob + c * HW]      = (float)(9 * 256 - 2 * acc0[c] - corr0[c]);
    out[ob + c * HW + W_] = (float)(9 * 256 - 2 * acc1[c] - corr1[c]);
  }
}

// ==================================================================
extern "C" void kernel_launch(void* const* d_in, const int* in_sizes, int n_in,
                              void* d_out, int out_size, void* d_ws, size_t ws_size,
                              hipStream_t stream) {
  const float* x     = (const float*)d_in[0];
  const float* alpha = (const float*)d_in[1];
  const float* wt    = (const float*)d_in[2];
  float* out = (float*)d_out;

  const size_t needA = (size_t)B_ * HP * HP * 256;   // 27,557,888 B
  const size_t needW = (size_t)9 * 8 * 8 * 64 * 16;  //    589,824 B

  if (ws_size >= needA + needW) {
    char* A8 = (char*)d_ws;
    v4i* Wf  = (v4i*)(A8 + needA);
    pack_a8_kernel<<<dim3(15, 32), 256, 0, stream>>>(x, alpha, A8);
    pack_w8_kernel<<<144, 256, 0, stream>>>(wt, Wf);
    conv_mfma_kernel<<<dim3(32 * 28 * 2), 256, 0, stream>>>(A8, Wf, out);
  } else {
    uint32_t* Ap = (uint32_t*)d_ws;
    uint32_t* Wp = Ap + (size_t)B_ * HP * HP * 8;
    uint32_t* pw = Wp + (size_t)9 * COUT * 8;
    dim3 gA((HP + 3) / 4, B_);
    pack_a_kernel<<<gA, 256, 0, stream>>>(x, alpha, Ap);
    pack_w_kernel<<<9, 256, 0, stream>>>(wt, Wp, pw);
    dim3 gC(COUT / NCO, H_ / (4 * OHT), B_);
    conv_kernel<<<gC, 256, 0, stream>>>(Ap, Wp, pw, out);
  }
}

// Round 6
// 104.621 us; speedup vs baseline: 1.9802x; 1.5754x over previous
//
#include <hip/hip_runtime.h>
#include <cstdint>

#define B_   32
#define CIN  256
#define COUT 256
#define H_   56
#define W_   56
#define HP   58          // padded spatial dim (pad=1 each side)
#define HW   (H_ * W_)   // 3136
#define WP   58          // LDS ww extent

typedef int v4i  __attribute__((ext_vector_type(4)));
typedef int v16i __attribute__((ext_vector_type(16)));

// ==================================================================
// XNOR conv via i8 MFMA: a,w in {+1,-1}; zero-pad = i8 0 (exact).
// ==================================================================

// ---- pack_a8: NCHW fp32 -> padded NHWC i8. A8[b][hh][ww][ci] ----
__global__ __launch_bounds__(256) void pack_a8_kernel(
    const float* __restrict__ x, const float* __restrict__ alpha,
    char* __restrict__ A8) {
  const int w = threadIdx.x & 63;
  const int q = threadIdx.x >> 6;
  const int hh = blockIdx.x * 4 + q;
  const int b = blockIdx.y;
  if (hh >= HP) return;
  char* rowbase = A8 + (size_t)(b * HP + hh) * (HP * 256);
  const uint4 z = make_uint4(0u, 0u, 0u, 0u);
  if (hh == 0 || hh == HP - 1) {           // border row: all zeros
    for (int i = w; i < HP * 16; i += 64) *(uint4*)(rowbase + i * 16) = z;
    return;
  }
  const int h = hh - 1;
  if (w < W_) {
    char* dst = rowbase + (w + 1) * 256;
    const float* xp = x + (size_t)b * CIN * HW + h * W_ + w;
    for (int cw = 0; cw < 16; ++cw) {      // 16B of channels per iter
      uint32_t wd[4];
      #pragma unroll
      for (int u = 0; u < 4; ++u) {
        uint32_t word = 0;
        #pragma unroll
        for (int bb = 0; bb < 4; ++bb) {
          int c = cw * 16 + u * 4 + bb;
          float v = xp[(size_t)c * HW];
          word |= ((v > alpha[c]) ? 0x01u : 0xFFu) << (bb * 8);
        }
        wd[u] = word;
      }
      *(uint4*)(dst + cw * 16) = *(uint4*)wd;
    }
  } else if (w == 56 || w == 57) {         // border pixels ww=0 / ww=57
    char* dst = rowbase + ((w == 56) ? 0 : (HP - 1)) * 256;
    #pragma unroll
    for (int i = 0; i < 16; ++i) *(uint4*)(dst + i * 16) = z;
  }
}

// ---- pack_w8: W in exact B-fragment form (HW-verified, absmax 0) ----
// Wf[((tap*8 + kc)*8 + ng)*64 + lane]: co = ng*32 + (lane&31),
// ci = kc*32 + (lane>>5)*16 + byte j
__global__ __launch_bounds__(256) void pack_w8_kernel(
    const float* __restrict__ wt, v4i* __restrict__ Wf) {
  int id = blockIdx.x * 256 + threadIdx.x;   // 36864 total
  int lane = id & 63;
  int ng = (id >> 6) & 7;
  int kc = (id >> 9) & 7;
  int tap = id >> 12;
  if (tap >= 9) return;
  int kh = tap / 3, kw = tap - kh * 3;
  int co = ng * 32 + (lane & 31);
  int cib = kc * 32 + (lane >> 5) * 16;
  uint32_t wd[4];
  #pragma unroll
  for (int u = 0; u < 4; ++u) {
    uint32_t word = 0;
    #pragma unroll
    for (int bb = 0; bb < 4; ++bb) {
      int ci = cib + u * 4 + bb;
      float v = wt[((size_t)(co * CIN + ci) * 3 + kh) * 3 + kw];
      word |= ((v > 0.0f) ? 0x01u : 0xFFu) << (bb * 8);
    }
    wd[u] = word;
  }
  Wf[id] = *(v4i*)wd;
}

// ---- conv_mfma v3 ----
// Block: 256 thr / 4 waves. Tile M128 (2 oh x 64 ow, full row) x N256.
// Wave wn: M128 x N64 -> acc[4 mg][2 ng] v16i = 128 VGPR.
// Loop: kc OUTER (8), taps inner: per kc load 18 Wf regs (amortized over
// 72 MFMAs), 24 conflict-free LDS af reads (transposed slab, imm offsets).
// Epilogue: per-ng transpose via LDS -> 448B aligned full-line stores.
__global__ __launch_bounds__(256, 2) void conv_mfma_kernel(
    const char* __restrict__ A8, const v4i* __restrict__ Wf,
    float* __restrict__ out) {
  __shared__ alignas(16) char lds[65536];
  const int tid = threadIdx.x;
  const int lane = tid & 63;
  const int l31 = lane & 31;
  const int hi  = lane >> 5;
  const int wn  = tid >> 6;

  const int ohp = blockIdx.x % 28;
  const int b   = blockIdx.x / 28;
  const int oh0 = ohp * 2;

  // ---- fill transposed slab: phys = ((gr*4 + rr)*WP + ww)*16 ----
  {
    const char* src0 = A8 + (size_t)(b * HP + oh0) * (HP * 256);
    for (int i = tid; i < 4 * WP * 16; i += 256) {
      int gr = i & 15;
      int pix = i >> 4;              // rr*WP + ww
      int rr = pix / WP;
      int ww = pix - rr * WP;
      uint4 v = *(const uint4*)(src0 + (size_t)(rr * HP + ww) * 256 + gr * 16);
      *(uint4*)(lds + ((gr * 4 + rr) * WP + ww) * 16) = v;
    }
  }
  __syncthreads();

  // per-thread A bases for the 6 ww windows (clamped; clamp lanes discarded)
  const char* aB = lds + hi * 3712;    // gr-half offset: 16*4*WP... hi*2*4*WP*16/2
  int woff[6];
  #pragma unroll
  for (int ws = 0; ws < 6; ++ws) {
    int ww = (ws / 3) * 32 + l31 + (ws % 3);
    if (ww > 57) ww = 57;
    woff[ws] = ww * 16;
  }

  v16i acc[4][2];
  #pragma unroll
  for (int m = 0; m < 4; ++m)
    #pragma unroll
    for (int n = 0; n < 2; ++n)
      #pragma unroll
      for (int e = 0; e < 16; ++e) acc[m][n][e] = 0;

  const v4i* wbase = Wf + (wn * 2) * 64 + lane;

  #pragma unroll
  for (int kc = 0; kc < 8; ++kc) {
    // W batch for this kc: 18 v4i (9 taps x 2 ng)
    v4i bf[9][2];
    #pragma unroll
    for (int tap = 0; tap < 9; ++tap) {
      bf[tap][0] = wbase[(tap * 8 + kc) * 512];
      bf[tap][1] = wbase[(tap * 8 + kc) * 512 + 64];
    }
    #pragma unroll
    for (int rr = 0; rr < 4; ++rr) {
      #pragma unroll
      for (int ws = 0; ws < 6; ++ws) {
        v4i af = *(const v4i*)(aB + woff[ws] + kc * 7424 + rr * 928);
        const int owh = ws / 3, kw = ws % 3;
        const int olo = (rr >= 3) ? 1 : 0;
        const int ohi = (rr >= 1) ? 1 : 0;
        #pragma unroll
        for (int ohl = olo; ohl <= ohi; ++ohl) {
          const int mg = ohl * 2 + owh;
          const int tap = (rr - ohl) * 3 + kw;
          acc[mg][0] = __builtin_amdgcn_mfma_i32_32x32x32_i8(af, bf[tap][0], acc[mg][0], 0, 0, 0);
          acc[mg][1] = __builtin_amdgcn_mfma_i32_32x32x32_i8(af, bf[tap][1], acc[mg][1], 0, 0, 0);
        }
      }
    }
  }

  // ---- epilogue: transpose via LDS (slab dead), aligned 448B/co stores ----
  __syncthreads();
  char* scr = lds + wn * 16384;      // 16KB per-wave region

  #pragma unroll
  for (int ng = 0; ng < 2; ++ng) {
    // write C[m][co=l31] -> scr[co][m], XOR-swizzled 16B slots
    #pragma unroll
    for (int mg = 0; mg < 4; ++mg) {
      #pragma unroll
      for (int q = 0; q < 4; ++q) {
        float4 f;
        f.x = (float)acc[mg][ng][q * 4 + 0];
        f.y = (float)acc[mg][ng][q * 4 + 1];
        f.z = (float)acc[mg][ng][q * 4 + 2];
        f.w = (float)acc[mg][ng][q * 4 + 3];
        int m0 = mg * 32 + q * 8 + hi * 4;
        int off = (l31 * 512 + m0 * 4) ^ ((l31 & 7) << 4);
        *(float4*)(scr + off) = f;
      }
    }
    __builtin_amdgcn_s_waitcnt(0);
    // read scr[co][m] rows, store 448B (28 float4) per co, line-aligned
    const int co0 = (wn * 2 + ng) * 32;
    #pragma unroll
    for (int t = 0; t < 14; ++t) {
      int f = t * 64 + lane;         // 0..895 = co_l*28 + s
      int co_l = f / 28;
      int s = f - co_l * 28;
      int u = s * 4;                 // float idx within 112-float chunk
      int ohl = (u >= 56) ? 1 : 0;
      int m0 = ohl * 64 + (u - ohl * 56);
      int off = (co_l * 512 + m0 * 4) ^ ((co_l & 7) << 4);
      float4 v = *(const float4*)(scr + off);
      float* op = out + ((size_t)(b * COUT + co0 + co_l) * H_ + oh0) * W_ + u;
      *(float4*)op = v;
    }
    __builtin_amdgcn_s_waitcnt(0);   // reads done before next ng overwrites
  }
}

// ==================================================================
extern "C" void kernel_launch(void* const* d_in, const int* in_sizes, int n_in,
                              void* d_out, int out_size, void* d_ws, size_t ws_size,
                              hipStream_t stream) {
  const float* x     = (const float*)d_in[0];
  const float* alpha = (const float*)d_in[1];
  const float* wt    = (const float*)d_in[2];
  float* out = (float*)d_out;

  const size_t needA = (size_t)B_ * HP * HP * 256;   // 27,557,888 B
  char* A8 = (char*)d_ws;
  v4i* Wf  = (v4i*)(A8 + needA);

  pack_a8_kernel<<<dim3(15, 32), 256, 0, stream>>>(x, alpha, A8);
  pack_w8_kernel<<<144, 256, 0, stream>>>(wt, Wf);
  conv_mfma_kernel<<<dim3(B_ * 28), 256, 0, stream>>>(A8, Wf, out);
}

// Round 7
// 100.962 us; speedup vs baseline: 2.0520x; 1.0362x over previous
//
#include <hip/hip_runtime.h>
#include <cstdint>

#define B_   32
#define CIN  256
#define COUT 256
#define H_   56
#define W_   56
#define HP   58          // padded spatial dim (pad=1 each side)
#define HW   (H_ * W_)   // 3136
#define WWIN 34          // slab ww window (32 ow + 2 halo)
#define WPAD 35          // padded ww extent in LDS

typedef int v4i  __attribute__((ext_vector_type(4)));
typedef int v16i __attribute__((ext_vector_type(16)));

// ==================================================================
// XNOR conv via i8 MFMA: a,w in {+1,-1}; zero-pad = i8 0 (exact).
// ==================================================================

// ---- pack_a8: NCHW fp32 -> padded NHWC i8. A8[b][hh][ww][ci] ----
__global__ __launch_bounds__(256) void pack_a8_kernel(
    const float* __restrict__ x, const float* __restrict__ alpha,
    char* __restrict__ A8) {
  const int w = threadIdx.x & 63;
  const int q = threadIdx.x >> 6;
  const int hh = blockIdx.x * 4 + q;
  const int b = blockIdx.y;
  if (hh >= HP) return;
  char* rowbase = A8 + (size_t)(b * HP + hh) * (HP * 256);
  const uint4 z = make_uint4(0u, 0u, 0u, 0u);
  if (hh == 0 || hh == HP - 1) {           // border row: all zeros
    for (int i = w; i < HP * 16; i += 64) *(uint4*)(rowbase + i * 16) = z;
    return;
  }
  const int h = hh - 1;
  if (w < W_) {
    char* dst = rowbase + (w + 1) * 256;
    const float* xp = x + (size_t)b * CIN * HW + h * W_ + w;
    for (int cw = 0; cw < 16; ++cw) {      // 16B of channels per iter
      uint32_t wd[4];
      #pragma unroll
      for (int u = 0; u < 4; ++u) {
        uint32_t word = 0;
        #pragma unroll
        for (int bb = 0; bb < 4; ++bb) {
          int c = cw * 16 + u * 4 + bb;
          float v = xp[(size_t)c * HW];
          word |= ((v > alpha[c]) ? 0x01u : 0xFFu) << (bb * 8);
        }
        wd[u] = word;
      }
      *(uint4*)(dst + cw * 16) = *(uint4*)wd;
    }
  } else if (w == 56 || w == 57) {         // border pixels ww=0 / ww=57
    char* dst = rowbase + ((w == 56) ? 0 : (HP - 1)) * 256;
    #pragma unroll
    for (int i = 0; i < 16; ++i) *(uint4*)(dst + i * 16) = z;
  }
}

// ---- pack_w8: W in exact B-fragment form (HW-verified, absmax 0) ----
// Wf[((tap*8 + kc)*8 + ng)*64 + lane]: co = ng*32 + (lane&31),
// ci = kc*32 + (lane>>5)*16 + byte j
__global__ __launch_bounds__(256) void pack_w8_kernel(
    const float* __restrict__ wt, v4i* __restrict__ Wf) {
  int id = blockIdx.x * 256 + threadIdx.x;   // 36864 total
  int lane = id & 63;
  int ng = (id >> 6) & 7;
  int kc = (id >> 9) & 7;
  int tap = id >> 12;
  if (tap >= 9) return;
  int kh = tap / 3, kw = tap - kh * 3;
  int co = ng * 32 + (lane & 31);
  int cib = kc * 32 + (lane >> 5) * 16;
  uint32_t wd[4];
  #pragma unroll
  for (int u = 0; u < 4; ++u) {
    uint32_t word = 0;
    #pragma unroll
    for (int bb = 0; bb < 4; ++bb) {
      int ci = cib + u * 4 + bb;
      float v = wt[((size_t)(co * CIN + ci) * 3 + kh) * 3 + kw];
      word |= ((v > 0.0f) ? 0x01u : 0xFFu) << (bb * 8);
    }
    wd[u] = word;
  }
  Wf[id] = *(v4i*)wd;
}

// ---- conv_mfma v4 ----
// Block: 256 thr / 4 waves. Tile M64 (2 oh x 32 ow) x N256.
// Wave wn: M64 x N64 -> acc[2 mg(oh)][2 ng] v16i = 64 regs.
// Slab: 4 rr x 34 ww x 256 ci transposed = 35,840 B -> 4 blocks/CU (LDS);
// launch_bounds(256,3) -> 3 waves/SIMD (VGPR) => 12 waves/CU.
// Per kc (x8): 3 kh-batches of {6 bf loads, 6 af reads, 12 MFMAs}.
// Epilogue: per-wave 8KB scr (reuses dead slab), 16-slot XOR swizzle,
// 128B/96B full-line row stores.
__global__ __launch_bounds__(256, 3) void conv_mfma_kernel(
    const char* __restrict__ A8, const v4i* __restrict__ Wf,
    float* __restrict__ out) {
  __shared__ alignas(16) char lds[16 * 4 * WPAD * 16];   // 35,840 B
  const int tid = threadIdx.x;
  const int lane = tid & 63;
  const int l31 = lane & 31;
  const int hi  = lane >> 5;
  const int wn  = tid >> 6;

  const int bx = blockIdx.x;
  const int owc = bx & 1;
  const int rest = bx >> 1;
  const int ohp = rest % 28;
  const int b   = rest / 28;
  const int oh0 = ohp * 2;
  const int owbase = owc * 32;

  // ---- fill transposed slab: phys = ((gr*4 + rr)*WPAD + wwl)*16 ----
  {
    const char* srcB = A8 + ((size_t)(b * HP + oh0) * HP + owbase) * 256;
    for (int i = tid; i < 4 * WWIN * 16; i += 256) {
      int gr = i & 15;
      int pix = i >> 4;              // rr*34 + wwl
      int rr = pix / WWIN;
      int wwl = pix - rr * WWIN;
      uint4 v = make_uint4(0u, 0u, 0u, 0u);
      if (owbase + wwl < HP)
        v = *(const uint4*)(srcB + ((size_t)rr * HP + wwl) * 256 + gr * 16);
      *(uint4*)(lds + ((gr * 4 + rr) * WPAD + wwl) * 16) = v;
    }
  }
  __syncthreads();

  v16i acc[2][2];
  #pragma unroll
  for (int m = 0; m < 2; ++m)
    #pragma unroll
    for (int n = 0; n < 2; ++n)
      #pragma unroll
      for (int e = 0; e < 16; ++e) acc[m][n][e] = 0;

  // thread-constant bases; all offsets are compile-time immediates
  const char* aB = lds + hi * (2 * 4 * WPAD * 16 / 2) + l31 * 16;  // hi*2240 + l31*16
  const v4i* wbase = Wf + (wn * 2) * 64 + lane;

  #pragma unroll
  for (int kc = 0; kc < 8; ++kc) {
    #pragma unroll
    for (int kh = 0; kh < 3; ++kh) {
      v4i b0[3], b1[3];
      #pragma unroll
      for (int kw = 0; kw < 3; ++kw) {
        b0[kw] = wbase[((kh * 3 + kw) * 8 + kc) * 512];
        b1[kw] = wbase[((kh * 3 + kw) * 8 + kc) * 512 + 64];
      }
      #pragma unroll
      for (int kw = 0; kw < 3; ++kw) {
        // af byte offset = kc*4480 + rr*560 + kw*16
        v4i a0 = *(const v4i*)(aB + kc * 4480 + (kh + 0) * 560 + kw * 16);
        v4i a1 = *(const v4i*)(aB + kc * 4480 + (kh + 1) * 560 + kw * 16);
        acc[0][0] = __builtin_amdgcn_mfma_i32_32x32x32_i8(a0, b0[kw], acc[0][0], 0, 0, 0);
        acc[0][1] = __builtin_amdgcn_mfma_i32_32x32x32_i8(a0, b1[kw], acc[0][1], 0, 0, 0);
        acc[1][0] = __builtin_amdgcn_mfma_i32_32x32x32_i8(a1, b0[kw], acc[1][0], 0, 0, 0);
        acc[1][1] = __builtin_amdgcn_mfma_i32_32x32x32_i8(a1, b1[kw], acc[1][1], 0, 0, 0);
      }
    }
  }

  // ---- epilogue: per-wave transpose via dead slab, full-line stores ----
  __syncthreads();
  char* scr = lds + wn * 8192;       // 8KB per wave: [co 32][m 64 floats]

  #pragma unroll
  for (int ng = 0; ng < 2; ++ng) {
    #pragma unroll
    for (int mg = 0; mg < 2; ++mg) {
      #pragma unroll
      for (int q = 0; q < 4; ++q) {
        float4 f;
        f.x = (float)acc[mg][ng][q * 4 + 0];
        f.y = (float)acc[mg][ng][q * 4 + 1];
        f.z = (float)acc[mg][ng][q * 4 + 2];
        f.w = (float)acc[mg][ng][q * 4 + 3];
        // m = q*8 + hi*4 + j, byte = mg*128 + q*32 + hi*16, granule XOR co
        int off = l31 * 256 + ((mg * 128 + q * 32 + hi * 16) ^ ((l31 & 15) << 4));
        *(float4*)(scr + off) = f;
      }
    }
    __builtin_amdgcn_s_waitcnt(0);
    const int co0 = (wn * 2 + ng) * 32;
    #pragma unroll
    for (int t = 0; t < 8; ++t) {
      int f = t * 64 + lane;         // 0..511 = co_l*16 + rem
      int co_l = f >> 4;
      int rem = f & 15;
      int mg = rem >> 3;
      int sq = rem & 7;
      int owl = sq * 4;
      if (owbase + owl <= 52) {      // last float = ow+3 <= 55
        float4 v = *(const float4*)(scr + co_l * 256 +
                                    ((mg * 128 + sq * 16) ^ ((co_l & 15) << 4)));
        float* op = out + ((size_t)(b * COUT + co0 + co_l) * H_ + oh0 + mg) * W_ +
                    owbase + owl;
        *(float4*)op = v;
      }
    }
    __builtin_amdgcn_s_waitcnt(0);   // reads done before next ng overwrites
  }
}

// ==================================================================
extern "C" void kernel_launch(void* const* d_in, const int* in_sizes, int n_in,
                              void* d_out, int out_size, void* d_ws, size_t ws_size,
                              hipStream_t stream) {
  const float* x     = (const float*)d_in[0];
  const float* alpha = (const float*)d_in[1];
  const float* wt    = (const float*)d_in[2];
  float* out = (float*)d_out;

  const size_t needA = (size_t)B_ * HP * HP * 256;   // 27,557,888 B
  char* A8 = (char*)d_ws;
  v4i* Wf  = (v4i*)(A8 + needA);

  pack_a8_kernel<<<dim3(15, 32), 256, 0, stream>>>(x, alpha, A8);
  pack_w8_kernel<<<144, 256, 0, stream>>>(wt, Wf);
  conv_mfma_kernel<<<dim3(B_ * 28 * 2), 256, 0, stream>>>(A8, Wf, out);
}